// Round 1
// baseline (5003.601 us; speedup 1.0000x reference)
//
#include <hip/hip_runtime.h>
#include <math.h>

// CorrectionRegressor fused kernel, fp32 VALU version (baseline).
// B=262144 rows; per block: 64 rows, 512 threads (8 waves), 2 blocks/CU.

#define THREADS 512
#define ROWS 64

__device__ __forceinline__ float gelu_f(float v) {
  // exact (erf) GELU, matches jax.nn.gelu(approximate=False)
  return 0.5f * v * (1.0f + erff(v * 0.70710678118654752f));
}

__global__ __launch_bounds__(THREADS, 4)
void corr_reg_fused(
    const float* __restrict__ x,
    const int*   __restrict__ mol_idx,
    const int*   __restrict__ iso_idx,
    const float* __restrict__ mol_embed,
    const float* __restrict__ iso_embed,
    const float* __restrict__ W1,  const float* __restrict__ b1,
    const float* __restrict__ g1,  const float* __restrict__ be1,
    const float* __restrict__ W2,  const float* __restrict__ b2,
    const float* __restrict__ g2,  const float* __restrict__ be2,
    const float* __restrict__ Wsh1, const float* __restrict__ bsh1,
    const float* __restrict__ Wsh2, const float* __restrict__ bsh2,
    const float* __restrict__ Wiso1, const float* __restrict__ biso1,
    const float* __restrict__ Wiso2, const float* __restrict__ biso2,
    const float* __restrict__ Wg,   const float* __restrict__ bg,
    float* __restrict__ out)
{
  // LDS: 8K (z) + 66.56K (buf) + ~1.6K misc  ~= 76.4 KB -> 2 blocks/CU
  __shared__ float z[ROWS][32];      // [x(16) | mol_e(8) | iso_e(8)]
  __shared__ float buf[ROWS][260];   // y1/h1 (256 cols), reused for y2/shared (128 cols). 260 floats = 65*16B: rows stay 16B-aligned.
  __shared__ float sp[ROWS];         // shared_pred per row
  __shared__ float eo[ROWS];         // expert out per row
  __shared__ float gLUT[12];         // sigmoid gate per iso
  __shared__ int   iso_s[ROWS];
  __shared__ unsigned char rowlist[12][ROWS];
  __shared__ int   rcount[12];

  const int t  = threadIdx.x;
  const int r0 = blockIdx.x * ROWS;

  if (t < 12) rcount[t] = 0;
  __syncthreads();

  // ---------------- phase 0: stage z, iso lists, gate LUT ----------------
  if (t < 256) {
    float4 v = ((const float4*)(x + (size_t)r0 * 16))[t];
    int r = t >> 2, c = (t & 3) << 2;
    z[r][c] = v.x; z[r][c + 1] = v.y; z[r][c + 2] = v.z; z[r][c + 3] = v.w;
  }
  {
    int r = t >> 3, e = t & 7;          // 64 rows x 8 lanes
    int mi = mol_idx[r0 + r];
    int ii = iso_idx[r0 + r];
    z[r][16 + e] = mol_embed[mi * 8 + e];
    z[r][24 + e] = iso_embed[ii * 8 + e];
    if (e == 0) {
      iso_s[r] = ii;
      int pos = atomicAdd(&rcount[ii], 1);
      rowlist[ii][pos] = (unsigned char)r;
    }
  }
  if (t >= THREADS - 12) {              // 12 threads: gate LUT
    int i = t - (THREADS - 12);
    float s = bg[0];
    #pragma unroll
    for (int e = 0; e < 8; e++) s += iso_embed[i * 8 + e] * Wg[e];
    gLUT[i] = 1.0f / (1.0f + expf(-s));
  }
  __syncthreads();

  // ---------------- phase 1: y1 = z @ W1 + b1  (thread = neuron) ----------
  {
    int n = t & 255, half = t >> 8;     // half: rows [half*32, half*32+32)
    float w1c[32];
    #pragma unroll
    for (int k = 0; k < 32; k++) w1c[k] = W1[k * 256 + n];
    float bn = b1[n];
    for (int rr = 0; rr < 32; rr += 4) {
      int r = half * 32 + rr;
      float a0 = bn, a1 = bn, a2 = bn, a3 = bn;
      #pragma unroll
      for (int k = 0; k < 32; k += 4) {
        float4 z0 = *(const float4*)&z[r + 0][k];
        float4 z1 = *(const float4*)&z[r + 1][k];
        float4 z2 = *(const float4*)&z[r + 2][k];
        float4 z3 = *(const float4*)&z[r + 3][k];
        a0 += z0.x * w1c[k] + z0.y * w1c[k+1] + z0.z * w1c[k+2] + z0.w * w1c[k+3];
        a1 += z1.x * w1c[k] + z1.y * w1c[k+1] + z1.z * w1c[k+2] + z1.w * w1c[k+3];
        a2 += z2.x * w1c[k] + z2.y * w1c[k+1] + z2.z * w1c[k+2] + z2.w * w1c[k+3];
        a3 += z3.x * w1c[k] + z3.y * w1c[k+1] + z3.z * w1c[k+2] + z3.w * w1c[k+3];
      }
      buf[r + 0][n] = a0; buf[r + 1][n] = a1;
      buf[r + 2][n] = a2; buf[r + 3][n] = a3;
    }
  }
  __syncthreads();

  // ---------------- LN1 + GELU (in place), 8 threads per row --------------
  {
    int r = t >> 3, sub = t & 7;        // 32 elems per thread
    float v[32];
    float s = 0.f, sq = 0.f;
    #pragma unroll
    for (int j = 0; j < 32; j++) {
      float y = buf[r][sub * 32 + j];
      v[j] = y; s += y; sq += y * y;
    }
    #pragma unroll
    for (int m = 1; m < 8; m <<= 1) { s += __shfl_xor(s, m); sq += __shfl_xor(sq, m); }
    float mu   = s * (1.0f / 256.0f);
    float var  = sq * (1.0f / 256.0f) - mu * mu;
    float rsig = rsqrtf(var + 1e-5f);
    #pragma unroll
    for (int j = 0; j < 32; j++) {
      int n = sub * 32 + j;
      float hn = (v[j] - mu) * rsig * g1[n] + be1[n];
      buf[r][n] = gelu_f(hn);
    }
  }
  __syncthreads();

  // ---------------- phase 2: y2 = h1 @ W2 + b2  (thread = neuron x 16 rows)
  {
    int n = t & 127, g = t >> 7;        // 4 groups x 16 rows
    float acc[16];
    float bn = b2[n];
    #pragma unroll
    for (int i = 0; i < 16; i++) acc[i] = bn;
    const float* w2p = W2 + n;
    for (int k = 0; k < 256; k += 4) {
      float w0 = w2p[(k + 0) * 128];
      float w1_ = w2p[(k + 1) * 128];
      float w2_ = w2p[(k + 2) * 128];
      float w3 = w2p[(k + 3) * 128];
      #pragma unroll
      for (int i = 0; i < 16; i++) {
        float4 h4 = *(const float4*)&buf[g * 16 + i][k];
        acc[i] += h4.x * w0 + h4.y * w1_ + h4.z * w2_ + h4.w * w3;
      }
    }
    __syncthreads();                    // everyone done READING h1
    #pragma unroll
    for (int i = 0; i < 16; i++) buf[g * 16 + i][n] = acc[i];
  }
  __syncthreads();

  // ---------------- LN2 + GELU (cols 0..127, in place) --------------------
  {
    int r = t >> 3, sub = t & 7;        // 16 elems per thread
    float v[16];
    float s = 0.f, sq = 0.f;
    #pragma unroll
    for (int j = 0; j < 16; j++) {
      float y = buf[r][sub * 16 + j];
      v[j] = y; s += y; sq += y * y;
    }
    #pragma unroll
    for (int m = 1; m < 8; m <<= 1) { s += __shfl_xor(s, m); sq += __shfl_xor(sq, m); }
    float mu   = s * (1.0f / 128.0f);
    float var  = sq * (1.0f / 128.0f) - mu * mu;
    float rsig = rsqrtf(var + 1e-5f);
    #pragma unroll
    for (int j = 0; j < 16; j++) {
      int n = sub * 16 + j;
      buf[r][n] = gelu_f((v[j] - mu) * rsig * g2[n] + be2[n]);
    }
  }
  __syncthreads();

  // ---------------- shared head: wave = row, lane = neuron ----------------
  {
    int n = t & 63, w = t >> 6;         // 8 waves, each does 8 rows
    float wsh2n = Wsh2[n];
    float bshn  = bsh1[n];
    for (int rr = 0; rr < 8; rr++) {
      int r = w * 8 + rr;
      float a0 = bshn, a1 = 0.f, a2 = 0.f, a3 = 0.f;
      for (int k = 0; k < 128; k += 4) {
        float4 h4 = *(const float4*)&buf[r][k];
        a0 += h4.x * Wsh1[(k + 0) * 64 + n];
        a1 += h4.y * Wsh1[(k + 1) * 64 + n];
        a2 += h4.z * Wsh1[(k + 2) * 64 + n];
        a3 += h4.w * Wsh1[(k + 3) * 64 + n];
      }
      #pragma unroll
      for (int e = 0; e < 8; e++) a0 += z[r][24 + e] * Wsh1[(128 + e) * 64 + n];
      float p = gelu_f((a0 + a1) + (a2 + a3)) * wsh2n;
      #pragma unroll
      for (int m = 1; m < 64; m <<= 1) p += __shfl_xor(p, m);
      if (n == 0) sp[r] = p + bsh2[0];
    }
  }

  // ---------------- expert head: iso-grouped (rows batched per iso) -------
  {
    int n = t & 63, w = t >> 6;         // wave = row slot, lane = neuron
    for (int i = 0; i < 12; i++) {
      int cnt = rcount[i];
      const float* wp = Wiso1 + (size_t)i * 128 * 64 + n;
      float w2n = Wiso2[i * 64 + n];
      float bi  = biso1[i * 64 + n];
      for (int base = 0; base < cnt; base += 8) {
        int idx = base + w;
        if (idx < cnt) {                // wave-uniform branch
          int r = rowlist[i][idx];
          float a0 = bi, a1 = 0.f, a2 = 0.f, a3 = 0.f;
          for (int k = 0; k < 128; k += 4) {
            float4 h4 = *(const float4*)&buf[r][k];
            a0 += h4.x * wp[(k + 0) * 64];
            a1 += h4.y * wp[(k + 1) * 64];
            a2 += h4.z * wp[(k + 2) * 64];
            a3 += h4.w * wp[(k + 3) * 64];
          }
          float p = gelu_f((a0 + a1) + (a2 + a3)) * w2n;
          #pragma unroll
          for (int m = 1; m < 64; m <<= 1) p += __shfl_xor(p, m);
          if (n == 0) eo[r] = p + biso2[i];
        }
      }
    }
  }
  __syncthreads();

  // ---------------- epilogue: gated combine -------------------------------
  if (t < ROWS) {
    int r = t;
    float gate = gLUT[iso_s[r]];
    out[r0 + r] = gate * eo[r] + (1.0f - gate) * sp[r];
  }
}

extern "C" void kernel_launch(void* const* d_in, const int* in_sizes, int n_in,
                              void* d_out, int out_size, void* d_ws, size_t ws_size,
                              hipStream_t stream) {
  const float* x         = (const float*)d_in[0];
  const int*   mol_idx   = (const int*)  d_in[1];
  const int*   iso_idx   = (const int*)  d_in[2];
  const float* mol_embed = (const float*)d_in[3];
  const float* iso_embed = (const float*)d_in[4];
  const float* W1  = (const float*)d_in[5];
  const float* b1  = (const float*)d_in[6];
  const float* g1  = (const float*)d_in[7];
  const float* be1 = (const float*)d_in[8];
  const float* W2  = (const float*)d_in[9];
  const float* b2  = (const float*)d_in[10];
  const float* g2  = (const float*)d_in[11];
  const float* be2 = (const float*)d_in[12];
  const float* Wsh1 = (const float*)d_in[13];
  const float* bsh1 = (const float*)d_in[14];
  const float* Wsh2 = (const float*)d_in[15];
  const float* bsh2 = (const float*)d_in[16];
  const float* Wiso1 = (const float*)d_in[17];
  const float* biso1 = (const float*)d_in[18];
  const float* Wiso2 = (const float*)d_in[19];
  const float* biso2 = (const float*)d_in[20];
  const float* Wg = (const float*)d_in[21];
  const float* bg = (const float*)d_in[22];
  float* out = (float*)d_out;

  const int B = in_sizes[0] / 16;       // 262144
  const int grid = B / ROWS;            // 4096 blocks

  hipLaunchKernelGGL(corr_reg_fused, dim3(grid), dim3(THREADS), 0, stream,
                     x, mol_idx, iso_idx, mol_embed, iso_embed,
                     W1, b1, g1, be1, W2, b2, g2, be2,
                     Wsh1, bsh1, Wsh2, bsh2,
                     Wiso1, biso1, Wiso2, biso2, Wg, bg, out);
}

// Round 2
// 1052.732 us; speedup vs baseline: 4.7530x; 4.7530x over previous
//
#include <hip/hip_runtime.h>
#include <math.h>

// CorrectionRegressor fused kernel, round 2: spill-free fp32 VALU version.
// B=262144 rows; per block: 32 rows, 256 threads (4 waves), 4 blocks/CU.

#define THREADS 256
#define ROWS 32

__device__ __forceinline__ float gelu_f(float v) {
  // exact (erf) GELU, matches jax.nn.gelu(approximate=False)
  return 0.5f * v * (1.0f + erff(v * 0.70710678118654752f));
}

__global__ __launch_bounds__(THREADS, 2)   // budget 256 VGPR either way; avoid r1's 64-VGPR spill trap
void corr_reg_fused(
    const float* __restrict__ x,
    const int*   __restrict__ mol_idx,
    const int*   __restrict__ iso_idx,
    const float* __restrict__ mol_embed,
    const float* __restrict__ iso_embed,
    const float* __restrict__ W1,  const float* __restrict__ b1,
    const float* __restrict__ g1,  const float* __restrict__ be1,
    const float* __restrict__ W2,  const float* __restrict__ b2,
    const float* __restrict__ g2,  const float* __restrict__ be2,
    const float* __restrict__ Wsh1, const float* __restrict__ bsh1,
    const float* __restrict__ Wsh2, const float* __restrict__ bsh2,
    const float* __restrict__ Wiso1, const float* __restrict__ biso1,
    const float* __restrict__ Wiso2, const float* __restrict__ biso2,
    const float* __restrict__ Wg,   const float* __restrict__ bg,
    float* __restrict__ out)
{
  // LDS ~= 38.3 KB -> 4 blocks/CU
  __shared__ float z[ROWS][32];      // [x(16) | mol_e(8) | iso_e(8)]
  __shared__ float buf[ROWS][260];   // y1/h1 (256 cols), reused for y2/shared (128 cols); 260*4B keeps rows 16B-aligned
  __shared__ float sp[ROWS];         // shared_pred per row
  __shared__ float eo[ROWS];         // expert out per row
  __shared__ float gLUT[12];         // sigmoid gate per iso
  __shared__ int   iso_s[ROWS];
  __shared__ unsigned char rowlist[12][ROWS];
  __shared__ unsigned char order[ROWS];   // rows sorted by iso (flattened)
  __shared__ int   rcount[12];
  __shared__ int   roff[12];

  const int t  = threadIdx.x;
  const int r0 = blockIdx.x * ROWS;

  if (t < 12) rcount[t] = 0;
  __syncthreads();

  // ---------------- phase 0: stage z, iso lists, gate LUT ----------------
  if (t < 128) {
    float4 v = ((const float4*)(x + (size_t)r0 * 16))[t];
    int r = t >> 2, c = (t & 3) << 2;
    z[r][c] = v.x; z[r][c + 1] = v.y; z[r][c + 2] = v.z; z[r][c + 3] = v.w;
  }
  {
    int r = t >> 3, e = t & 7;          // 32 rows x 8 lanes
    int mi = mol_idx[r0 + r];
    int ii = iso_idx[r0 + r];
    z[r][16 + e] = mol_embed[mi * 8 + e];
    z[r][24 + e] = iso_embed[ii * 8 + e];
    if (e == 0) {
      iso_s[r] = ii;
      int pos = atomicAdd(&rcount[ii], 1);
      rowlist[ii][pos] = (unsigned char)r;
    }
  }
  if (t >= THREADS - 12) {              // 12 threads: gate LUT
    int i = t - (THREADS - 12);
    float s = bg[0];
    #pragma unroll
    for (int e = 0; e < 8; e++) s += iso_embed[i * 8 + e] * Wg[e];
    gLUT[i] = 1.0f / (1.0f + expf(-s));
  }
  __syncthreads();

  // ---------------- phase 1: y1 = z @ W1 + b1  (thread = neuron) ----------
  if (t == 0) {                         // prefix-sum iso counts (tiny, overlapped)
    int a = 0;
    #pragma unroll
    for (int i = 0; i < 12; i++) { roff[i] = a; a += rcount[i]; }
  }
  {
    int n = t;                          // 256 neurons, each thread does all 32 rows
    float w1c[32];
    #pragma unroll
    for (int k = 0; k < 32; k++) w1c[k] = W1[k * 256 + n];
    float bn = b1[n];
    for (int r = 0; r < ROWS; r += 4) {
      float a0 = bn, a1 = bn, a2 = bn, a3 = bn;
      #pragma unroll
      for (int k = 0; k < 32; k += 4) {
        float4 z0 = *(const float4*)&z[r + 0][k];
        float4 z1 = *(const float4*)&z[r + 1][k];
        float4 z2 = *(const float4*)&z[r + 2][k];
        float4 z3 = *(const float4*)&z[r + 3][k];
        a0 += z0.x * w1c[k] + z0.y * w1c[k+1] + z0.z * w1c[k+2] + z0.w * w1c[k+3];
        a1 += z1.x * w1c[k] + z1.y * w1c[k+1] + z1.z * w1c[k+2] + z1.w * w1c[k+3];
        a2 += z2.x * w1c[k] + z2.y * w1c[k+1] + z2.z * w1c[k+2] + z2.w * w1c[k+3];
        a3 += z3.x * w1c[k] + z3.y * w1c[k+1] + z3.z * w1c[k+2] + z3.w * w1c[k+3];
      }
      buf[r + 0][n] = a0; buf[r + 1][n] = a1;
      buf[r + 2][n] = a2; buf[r + 3][n] = a3;
    }
  }
  __syncthreads();

  // ---------------- LN1 + GELU (in place), 8 threads per row --------------
  if (t < 12) {                         // flatten iso row lists (roff ready)
    int c = rcount[t], o = roff[t];
    for (int p = 0; p < c; p++) order[o + p] = rowlist[t][p];
  }
  {
    int r = t >> 3, sub = t & 7;        // 8 float4 per thread, bank-uniform pattern
    float4 v[8];
    float s = 0.f, sq = 0.f;
    #pragma unroll
    for (int m = 0; m < 8; m++) {
      v[m] = *(const float4*)&buf[r][m * 32 + sub * 4];
      s  += (v[m].x + v[m].y) + (v[m].z + v[m].w);
      sq += (v[m].x * v[m].x + v[m].y * v[m].y) + (v[m].z * v[m].z + v[m].w * v[m].w);
    }
    #pragma unroll
    for (int m = 1; m < 8; m <<= 1) { s += __shfl_xor(s, m); sq += __shfl_xor(sq, m); }
    float mu   = s * (1.0f / 256.0f);
    float var  = sq * (1.0f / 256.0f) - mu * mu;
    float rsig = rsqrtf(var + 1e-5f);
    #pragma unroll
    for (int m = 0; m < 8; m++) {
      int c = m * 32 + sub * 4;
      float4 h;
      h.x = gelu_f((v[m].x - mu) * rsig * g1[c+0] + be1[c+0]);
      h.y = gelu_f((v[m].y - mu) * rsig * g1[c+1] + be1[c+1]);
      h.z = gelu_f((v[m].z - mu) * rsig * g1[c+2] + be1[c+2]);
      h.w = gelu_f((v[m].w - mu) * rsig * g1[c+3] + be1[c+3]);
      *(float4*)&buf[r][c] = h;
    }
  }
  __syncthreads();

  // ---------------- phase 2: y2 = h1 @ W2 + b2  (thread = neuron x 16 rows)
  {
    int n = t & 127, g = t >> 7;        // 2 groups x 16 rows
    float acc[16];
    float bn = b2[n];
    #pragma unroll
    for (int i = 0; i < 16; i++) acc[i] = bn;
    const float* w2p = W2 + n;
    for (int k = 0; k < 256; k += 4) {
      float w0  = w2p[(k + 0) * 128];
      float w1_ = w2p[(k + 1) * 128];
      float w2_ = w2p[(k + 2) * 128];
      float w3  = w2p[(k + 3) * 128];
      #pragma unroll
      for (int i = 0; i < 16; i++) {
        float4 h4 = *(const float4*)&buf[g * 16 + i][k];
        acc[i] += h4.x * w0 + h4.y * w1_ + h4.z * w2_ + h4.w * w3;
      }
    }
    __syncthreads();                    // everyone done READING h1
    #pragma unroll
    for (int i = 0; i < 16; i++) buf[g * 16 + i][n] = acc[i];
  }
  __syncthreads();

  // ---------------- LN2 + GELU (cols 0..127, in place) --------------------
  {
    int r = t >> 3, sub = t & 7;        // 4 float4 per thread
    float4 v[4];
    float s = 0.f, sq = 0.f;
    #pragma unroll
    for (int m = 0; m < 4; m++) {
      v[m] = *(const float4*)&buf[r][m * 32 + sub * 4];
      s  += (v[m].x + v[m].y) + (v[m].z + v[m].w);
      sq += (v[m].x * v[m].x + v[m].y * v[m].y) + (v[m].z * v[m].z + v[m].w * v[m].w);
    }
    #pragma unroll
    for (int m = 1; m < 8; m <<= 1) { s += __shfl_xor(s, m); sq += __shfl_xor(sq, m); }
    float mu   = s * (1.0f / 128.0f);
    float var  = sq * (1.0f / 128.0f) - mu * mu;
    float rsig = rsqrtf(var + 1e-5f);
    #pragma unroll
    for (int m = 0; m < 4; m++) {
      int c = m * 32 + sub * 4;
      float4 h;
      h.x = gelu_f((v[m].x - mu) * rsig * g2[c+0] + be2[c+0]);
      h.y = gelu_f((v[m].y - mu) * rsig * g2[c+1] + be2[c+1]);
      h.z = gelu_f((v[m].z - mu) * rsig * g2[c+2] + be2[c+2]);
      h.w = gelu_f((v[m].w - mu) * rsig * g2[c+3] + be2[c+3]);
      *(float4*)&buf[r][c] = h;
    }
  }
  __syncthreads();

  // ---------------- shared head: wave = row, lane = neuron ----------------
  {
    int n = t & 63, w = t >> 6;         // 4 waves, each does 8 rows
    float wsh2n = Wsh2[n];
    float bshn  = bsh1[n];
    for (int rr = 0; rr < 8; rr++) {
      int r = w * 8 + rr;
      float a0 = bshn, a1 = 0.f, a2 = 0.f, a3 = 0.f;
      for (int k = 0; k < 128; k += 4) {
        float4 h4 = *(const float4*)&buf[r][k];
        a0 += h4.x * Wsh1[(k + 0) * 64 + n];
        a1 += h4.y * Wsh1[(k + 1) * 64 + n];
        a2 += h4.z * Wsh1[(k + 2) * 64 + n];
        a3 += h4.w * Wsh1[(k + 3) * 64 + n];
      }
      #pragma unroll
      for (int e = 0; e < 8; e++) a0 += z[r][24 + e] * Wsh1[(128 + e) * 64 + n];
      float p = gelu_f((a0 + a1) + (a2 + a3)) * wsh2n;
      #pragma unroll
      for (int m = 1; m < 64; m <<= 1) p += __shfl_xor(p, m);
      if (n == 0) sp[r] = p + bsh2[0];
    }
  }

  // ---------------- expert head: flattened iso-sorted list ----------------
  {
    int n = t & 63, w = t >> 6;         // 4 waves x 8 slots = 32 rows, all busy
    for (int j = 0; j < 8; j++) {
      int slot = w * 8 + j;             // wave-uniform
      int r = order[slot];
      int i = iso_s[r];
      const float* wp = Wiso1 + (size_t)i * 128 * 64 + n;
      float a0 = biso1[i * 64 + n], a1 = 0.f, a2 = 0.f, a3 = 0.f;
      for (int k = 0; k < 128; k += 4) {
        float4 h4 = *(const float4*)&buf[r][k];
        a0 += h4.x * wp[(k + 0) * 64];
        a1 += h4.y * wp[(k + 1) * 64];
        a2 += h4.z * wp[(k + 2) * 64];
        a3 += h4.w * wp[(k + 3) * 64];
      }
      float p = gelu_f((a0 + a1) + (a2 + a3)) * Wiso2[i * 64 + n];
      #pragma unroll
      for (int m = 1; m < 64; m <<= 1) p += __shfl_xor(p, m);
      if (n == 0) eo[r] = p + biso2[i];
    }
  }
  __syncthreads();

  // ---------------- epilogue: gated combine -------------------------------
  if (t < ROWS) {
    int r = t;
    float gate = gLUT[iso_s[r]];
    out[r0 + r] = gate * eo[r] + (1.0f - gate) * sp[r];
  }
}

extern "C" void kernel_launch(void* const* d_in, const int* in_sizes, int n_in,
                              void* d_out, int out_size, void* d_ws, size_t ws_size,
                              hipStream_t stream) {
  const float* x         = (const float*)d_in[0];
  const int*   mol_idx   = (const int*)  d_in[1];
  const int*   iso_idx   = (const int*)  d_in[2];
  const float* mol_embed = (const float*)d_in[3];
  const float* iso_embed = (const float*)d_in[4];
  const float* W1  = (const float*)d_in[5];
  const float* b1  = (const float*)d_in[6];
  const float* g1  = (const float*)d_in[7];
  const float* be1 = (const float*)d_in[8];
  const float* W2  = (const float*)d_in[9];
  const float* b2  = (const float*)d_in[10];
  const float* g2  = (const float*)d_in[11];
  const float* be2 = (const float*)d_in[12];
  const float* Wsh1 = (const float*)d_in[13];
  const float* bsh1 = (const float*)d_in[14];
  const float* Wsh2 = (const float*)d_in[15];
  const float* bsh2 = (const float*)d_in[16];
  const float* Wiso1 = (const float*)d_in[17];
  const float* biso1 = (const float*)d_in[18];
  const float* Wiso2 = (const float*)d_in[19];
  const float* biso2 = (const float*)d_in[20];
  const float* Wg = (const float*)d_in[21];
  const float* bg = (const float*)d_in[22];
  float* out = (float*)d_out;

  const int B = in_sizes[0] / 16;       // 262144
  const int grid = B / ROWS;            // 8192 blocks

  hipLaunchKernelGGL(corr_reg_fused, dim3(grid), dim3(THREADS), 0, stream,
                     x, mol_idx, iso_idx, mol_embed, iso_embed,
                     W1, b1, g1, be1, W2, b2, g2, be2,
                     Wsh1, bsh1, Wsh2, bsh2,
                     Wiso1, biso1, Wiso2, biso2, Wg, bg, out);
}

// Round 3
// 496.372 us; speedup vs baseline: 10.0803x; 2.1209x over previous
//
#include <hip/hip_runtime.h>
#include <math.h>

// CorrectionRegressor fused kernel, round 3: MFMA (split-bf16) for layers 1+2,
// in-register LN stats, fp32 VALU heads with amortized weight loads.
// B=262144 rows; per block: 32 rows, 256 threads (4 waves), 4 blocks/CU.

#define THREADS 256
#define ROWS 32

typedef __attribute__((ext_vector_type(8))) short short8;
typedef __attribute__((ext_vector_type(4))) float f32x4;

__device__ __forceinline__ float gelu_f(float v) {
  return 0.5f * v * (1.0f + erff(v * 0.70710678118654752f));
}
__device__ __forceinline__ unsigned short f2bf(float f) {   // RNE f32->bf16
  unsigned int u = __float_as_uint(f);
  return (unsigned short)((u + 0x7FFFu + ((u >> 16) & 1u)) >> 16);
}
__device__ __forceinline__ float bf2f(unsigned short b) {
  return __uint_as_float(((unsigned int)b) << 16);
}
__device__ __forceinline__ float wave_sum64(float p) {
  #pragma unroll
  for (int m = 1; m < 64; m <<= 1) p += __shfl_xor(p, m);
  return p;
}

// ---- setup: convert W1/W2 to bf16 hi/lo MFMA B-fragment layout in d_ws ----
// w2f: [h(2)][ks(8)][nt(8)][lane(64)][j(8)]  value = W2[ks*32+(l>>4)*8+j][nt*16+(l&15)]
// w1f: [h(2)][nt(16)][lane(64)][j(8)]        value = W1[(l>>4)*8+j][nt*16+(l&15)]
__global__ void prep_frags(const float* __restrict__ W1, const float* __restrict__ W2,
                           unsigned short* __restrict__ wsf) {
  int id = blockIdx.x * 256 + threadIdx.x;
  if (id < 8192) {                      // W2 frags
    int l = id & 63, nt = (id >> 6) & 7, ks = (id >> 9) & 7, h = id >> 12;
    int n = nt * 16 + (l & 15);
    int k0 = ks * 32 + (l >> 4) * 8;
    unsigned short o[8];
    #pragma unroll
    for (int j = 0; j < 8; j++) {
      float v = W2[(k0 + j) * 128 + n];
      unsigned short hb = f2bf(v);
      o[j] = h ? f2bf(v - bf2f(hb)) : hb;
    }
    short8 pk;
    #pragma unroll
    for (int j = 0; j < 8; j++) pk[j] = (short)o[j];
    *(short8*)(wsf + (size_t)id * 8) = pk;
  } else if (id < 10240) {              // W1 frags
    int id2 = id - 8192;
    int l = id2 & 63, nt = (id2 >> 6) & 15, h = id2 >> 10;
    int n = nt * 16 + (l & 15);
    int k0 = (l >> 4) * 8;
    unsigned short o[8];
    #pragma unroll
    for (int j = 0; j < 8; j++) {
      float v = W1[(k0 + j) * 256 + n];
      unsigned short hb = f2bf(v);
      o[j] = h ? f2bf(v - bf2f(hb)) : hb;
    }
    short8 pk;
    #pragma unroll
    for (int j = 0; j < 8; j++) pk[j] = (short)o[j];
    *(short8*)(wsf + 65536 + (size_t)id2 * 8) = pk;
  }
}

__global__ __launch_bounds__(THREADS, 4)
void corr_reg_fused(
    const float* __restrict__ x,
    const int*   __restrict__ mol_idx,
    const int*   __restrict__ iso_idx,
    const float* __restrict__ mol_embed,
    const float* __restrict__ iso_embed,
    const float* __restrict__ b1,
    const float* __restrict__ g1,  const float* __restrict__ be1,
    const float* __restrict__ b2,
    const float* __restrict__ g2,  const float* __restrict__ be2,
    const float* __restrict__ Wsh1, const float* __restrict__ bsh1,
    const float* __restrict__ Wsh2, const float* __restrict__ bsh2,
    const float* __restrict__ Wiso1, const float* __restrict__ biso1,
    const float* __restrict__ Wiso2, const float* __restrict__ biso2,
    const float* __restrict__ Wg,   const float* __restrict__ bg,
    const unsigned short* __restrict__ wsf,
    float* __restrict__ out)
{
  // LDS total ~= 40.4 KB -> 4 blocks/CU
  __shared__ float z[ROWS][36];                       // pad 36: stride 4 mod 32 banks
  __shared__ __align__(16) unsigned short hpool[2][ROWS][264]; // h1 hi/lo bf16, pad 264 (16B-aligned rows)
  __shared__ float ps[4][ROWS], pq[4][ROWS];          // cross-wave LN partials
  __shared__ float sp[ROWS];
  __shared__ float eo[ROWS];
  __shared__ float gLUT[12];
  __shared__ int   iso_s[ROWS];
  __shared__ unsigned char rowlist[12][ROWS];
  __shared__ unsigned char order[ROWS];
  __shared__ int   rcount[12];
  __shared__ int   roff[12];

  float* shbuf = (float*)&hpool[0][0][0];             // alias: [32][132] f32 (16896B = hpool[0] exactly)

  const int t  = threadIdx.x;
  const int r0 = blockIdx.x * ROWS;
  const int l  = t & 63, w = t >> 6;                  // lane, wave
  const int lr = l & 15, lg = l >> 4;                 // MFMA row/col index, k-group

  if (t < 12) rcount[t] = 0;
  __syncthreads();

  // ---------------- phase 0: stage z, iso lists, gate LUT ----------------
  if (t < 128) {
    float4 v = ((const float4*)(x + (size_t)r0 * 16))[t];
    int r = t >> 2, c = (t & 3) << 2;
    z[r][c] = v.x; z[r][c + 1] = v.y; z[r][c + 2] = v.z; z[r][c + 3] = v.w;
  }
  {
    int r = t >> 3, e = t & 7;
    int mi = mol_idx[r0 + r];
    int ii = iso_idx[r0 + r];
    z[r][16 + e] = mol_embed[mi * 8 + e];
    z[r][24 + e] = iso_embed[ii * 8 + e];
    if (e == 0) {
      iso_s[r] = ii;
      int pos = atomicAdd(&rcount[ii], 1);
      rowlist[ii][pos] = (unsigned char)r;
    }
  }
  if (t >= THREADS - 12) {
    int i = t - (THREADS - 12);
    float s = bg[0];
    #pragma unroll
    for (int e = 0; e < 8; e++) s += iso_embed[i * 8 + e] * Wg[e];
    gLUT[i] = 1.0f / (1.0f + expf(-s));
  }
  __syncthreads();                                    // B1

  if (t == 0) {
    int a = 0;
    #pragma unroll
    for (int i = 0; i < 12; i++) { roff[i] = a; a += rcount[i]; }
  }

  // ---------------- layer 1 (MFMA): y1 = z @ W1 + b1 ----------------------
  f32x4 acc[2][4];
  {
    // z A-fragments (hi/lo) built in-register from LDS f32
    short8 zah[2], zal[2];
    #pragma unroll
    for (int mt = 0; mt < 2; mt++) {
      int row = mt * 16 + lr;
      float vv[8];
      *(float4*)&vv[0] = *(const float4*)&z[row][lg * 8];
      *(float4*)&vv[4] = *(const float4*)&z[row][lg * 8 + 4];
      short8 h8, l8;
      #pragma unroll
      for (int j = 0; j < 8; j++) {
        unsigned short hb = f2bf(vv[j]);
        unsigned short lb = f2bf(vv[j] - bf2f(hb));
        h8[j] = (short)hb; l8[j] = (short)lb;
      }
      zah[mt] = h8; zal[mt] = l8;
    }
    // B-fragments from precomputed global (L2-hot)
    const short8* w1p = (const short8*)(wsf + 65536);
    short8 bh[4], bl[4];
    #pragma unroll
    for (int q = 0; q < 4; q++) {
      int nt = w * 4 + q;
      bh[q] = w1p[nt * 64 + l];
      bl[q] = w1p[(16 + nt) * 64 + l];
    }
    #pragma unroll
    for (int mt = 0; mt < 2; mt++)
      #pragma unroll
      for (int q = 0; q < 4; q++) {
        f32x4 a_ = {0.f, 0.f, 0.f, 0.f};
        a_ = __builtin_amdgcn_mfma_f32_16x16x32_bf16(zah[mt], bh[q], a_, 0, 0, 0);
        a_ = __builtin_amdgcn_mfma_f32_16x16x32_bf16(zah[mt], bl[q], a_, 0, 0, 0);
        a_ = __builtin_amdgcn_mfma_f32_16x16x32_bf16(zal[mt], bh[q], a_, 0, 0, 0);
        acc[mt][q] = a_;
      }
    // bias + in-register LN1 stats
    float bc[4];
    #pragma unroll
    for (int q = 0; q < 4; q++) bc[q] = b1[(w * 4 + q) * 16 + lr];
    #pragma unroll
    for (int mt = 0; mt < 2; mt++)
      #pragma unroll
      for (int q = 0; q < 4; q++)
        #pragma unroll
        for (int i = 0; i < 4; i++) acc[mt][q][i] += bc[q];
    #pragma unroll
    for (int mt = 0; mt < 2; mt++)
      #pragma unroll
      for (int i = 0; i < 4; i++) {
        float sm = acc[mt][0][i] + acc[mt][1][i] + acc[mt][2][i] + acc[mt][3][i];
        float sq = acc[mt][0][i]*acc[mt][0][i] + acc[mt][1][i]*acc[mt][1][i]
                 + acc[mt][2][i]*acc[mt][2][i] + acc[mt][3][i]*acc[mt][3][i];
        #pragma unroll
        for (int m = 1; m < 16; m <<= 1) { sm += __shfl_xor(sm, m); sq += __shfl_xor(sq, m); }
        if (lr == 0) { ps[w][mt * 16 + lg * 4 + i] = sm; pq[w][mt * 16 + lg * 4 + i] = sq; }
      }
  }
  __syncthreads();                                    // B2

  if (t < 12) {                                       // flatten iso-sorted order
    int c = rcount[t], o = roff[t];
    for (int p = 0; p < c; p++) order[o + p] = rowlist[t][p];
  }

  // ---------------- LN1 + GELU + bf16 split, write h fragments ------------
  {
    float g1c[4], be1c[4];
    #pragma unroll
    for (int q = 0; q < 4; q++) {
      int col = (w * 4 + q) * 16 + lr;
      g1c[q] = g1[col]; be1c[q] = be1[col];
    }
    #pragma unroll
    for (int mt = 0; mt < 2; mt++)
      #pragma unroll
      for (int i = 0; i < 4; i++) {
        int row = mt * 16 + lg * 4 + i;
        float su = ps[0][row] + ps[1][row] + ps[2][row] + ps[3][row];
        float s2 = pq[0][row] + pq[1][row] + pq[2][row] + pq[3][row];
        float mu = su * (1.0f / 256.0f);
        float var = s2 * (1.0f / 256.0f) - mu * mu;
        float rs = rsqrtf(var + 1e-5f);
        #pragma unroll
        for (int q = 0; q < 4; q++) {
          int col = (w * 4 + q) * 16 + lr;
          float h = gelu_f((acc[mt][q][i] - mu) * rs * g1c[q] + be1c[q]);
          unsigned short hb = f2bf(h);
          unsigned short lb = f2bf(h - bf2f(hb));
          hpool[0][row][col] = hb;
          hpool[1][row][col] = lb;
        }
      }
  }
  __syncthreads();                                    // B3

  // ---------------- layer 2 (MFMA): y2 = h1 @ W2 + b2 ---------------------
  f32x4 a2[2][2];
  {
    #pragma unroll
    for (int mt = 0; mt < 2; mt++)
      #pragma unroll
      for (int q = 0; q < 2; q++) { f32x4 zf = {0.f,0.f,0.f,0.f}; a2[mt][q] = zf; }
    const short8* w2p = (const short8*)wsf;
    for (int ks = 0; ks < 8; ks++) {
      int k0 = ks * 32 + lg * 8;
      short8 ah0 = *(const short8*)&hpool[0][lr][k0];
      short8 al0 = *(const short8*)&hpool[1][lr][k0];
      short8 ah1 = *(const short8*)&hpool[0][16 + lr][k0];
      short8 al1 = *(const short8*)&hpool[1][16 + lr][k0];
      short8 bh0 = w2p[(ks * 8 + 2 * w + 0) * 64 + l];
      short8 bl0 = w2p[((8 + ks) * 8 + 2 * w + 0) * 64 + l];
      short8 bh1 = w2p[(ks * 8 + 2 * w + 1) * 64 + l];
      short8 bl1 = w2p[((8 + ks) * 8 + 2 * w + 1) * 64 + l];
      a2[0][0] = __builtin_amdgcn_mfma_f32_16x16x32_bf16(ah0, bh0, a2[0][0], 0, 0, 0);
      a2[0][0] = __builtin_amdgcn_mfma_f32_16x16x32_bf16(ah0, bl0, a2[0][0], 0, 0, 0);
      a2[0][0] = __builtin_amdgcn_mfma_f32_16x16x32_bf16(al0, bh0, a2[0][0], 0, 0, 0);
      a2[0][1] = __builtin_amdgcn_mfma_f32_16x16x32_bf16(ah0, bh1, a2[0][1], 0, 0, 0);
      a2[0][1] = __builtin_amdgcn_mfma_f32_16x16x32_bf16(ah0, bl1, a2[0][1], 0, 0, 0);
      a2[0][1] = __builtin_amdgcn_mfma_f32_16x16x32_bf16(al0, bh1, a2[0][1], 0, 0, 0);
      a2[1][0] = __builtin_amdgcn_mfma_f32_16x16x32_bf16(ah1, bh0, a2[1][0], 0, 0, 0);
      a2[1][0] = __builtin_amdgcn_mfma_f32_16x16x32_bf16(ah1, bl0, a2[1][0], 0, 0, 0);
      a2[1][0] = __builtin_amdgcn_mfma_f32_16x16x32_bf16(al1, bh0, a2[1][0], 0, 0, 0);
      a2[1][1] = __builtin_amdgcn_mfma_f32_16x16x32_bf16(ah1, bh1, a2[1][1], 0, 0, 0);
      a2[1][1] = __builtin_amdgcn_mfma_f32_16x16x32_bf16(ah1, bl1, a2[1][1], 0, 0, 0);
      a2[1][1] = __builtin_amdgcn_mfma_f32_16x16x32_bf16(al1, bh1, a2[1][1], 0, 0, 0);
    }
    float bc2[2];
    #pragma unroll
    for (int q = 0; q < 2; q++) bc2[q] = b2[(2 * w + q) * 16 + lr];
    #pragma unroll
    for (int mt = 0; mt < 2; mt++)
      #pragma unroll
      for (int q = 0; q < 2; q++)
        #pragma unroll
        for (int i = 0; i < 4; i++) a2[mt][q][i] += bc2[q];
    #pragma unroll
    for (int mt = 0; mt < 2; mt++)
      #pragma unroll
      for (int i = 0; i < 4; i++) {
        float sm = a2[mt][0][i] + a2[mt][1][i];
        float sq = a2[mt][0][i]*a2[mt][0][i] + a2[mt][1][i]*a2[mt][1][i];
        #pragma unroll
        for (int m = 1; m < 16; m <<= 1) { sm += __shfl_xor(sm, m); sq += __shfl_xor(sq, m); }
        if (lr == 0) { ps[w][mt * 16 + lg * 4 + i] = sm; pq[w][mt * 16 + lg * 4 + i] = sq; }
      }
  }
  __syncthreads();                                    // B4 (all h-frag reads done)

  // ---------------- LN2 + GELU, write shared f32 (aliased over hpool) -----
  {
    float g2c[2], be2c[2];
    #pragma unroll
    for (int q = 0; q < 2; q++) {
      int col = (2 * w + q) * 16 + lr;
      g2c[q] = g2[col]; be2c[q] = be2[col];
    }
    #pragma unroll
    for (int mt = 0; mt < 2; mt++)
      #pragma unroll
      for (int i = 0; i < 4; i++) {
        int row = mt * 16 + lg * 4 + i;
        float su = ps[0][row] + ps[1][row] + ps[2][row] + ps[3][row];
        float s2 = pq[0][row] + pq[1][row] + pq[2][row] + pq[3][row];
        float mu = su * (1.0f / 128.0f);
        float var = s2 * (1.0f / 128.0f) - mu * mu;
        float rs = rsqrtf(var + 1e-5f);
        #pragma unroll
        for (int q = 0; q < 2; q++) {
          int col = (2 * w + q) * 16 + lr;
          shbuf[row * 132 + col] = gelu_f((a2[mt][q][i] - mu) * rs * g2c[q] + be2c[q]);
        }
      }
  }
  __syncthreads();                                    // B5

  // ---------------- shared head (k-outer, weights amortized 8x) -----------
  {
    int n = l;
    int rbase = w * 8;
    float accs[8];
    float bn = bsh1[n];
    #pragma unroll
    for (int j = 0; j < 8; j++) accs[j] = bn;
    for (int k = 0; k < 128; k += 4) {
      const float* wp = Wsh1 + k * 64 + n;
      float w0 = wp[0], w1_ = wp[64], w2_ = wp[128], w3 = wp[192];
      #pragma unroll
      for (int j = 0; j < 8; j++) {
        float4 h4 = *(const float4*)&shbuf[(rbase + j) * 132 + k];
        accs[j] += h4.x * w0 + h4.y * w1_ + h4.z * w2_ + h4.w * w3;
      }
    }
    #pragma unroll
    for (int e = 0; e < 8; e++) {
      float we = Wsh1[(128 + e) * 64 + n];
      #pragma unroll
      for (int j = 0; j < 8; j++) accs[j] += z[rbase + j][24 + e] * we;
    }
    float wsh2n = Wsh2[n];
    #pragma unroll
    for (int j = 0; j < 8; j++) {
      float p = wave_sum64(gelu_f(accs[j]) * wsh2n);
      if (n == 0) sp[rbase + j] = p + bsh2[0];
    }
  }

  // ---------------- expert head (iso-sorted, k-outer, reload on iso change)
  {
    int n = l;
    int rows_[8], isos[8];
    #pragma unroll
    for (int j = 0; j < 8; j++) {
      int r = order[w * 8 + j];
      rows_[j] = r; isos[j] = iso_s[r];
    }
    float acce[8];
    #pragma unroll
    for (int j = 0; j < 8; j++) acce[j] = biso1[isos[j] * 64 + n];
    for (int k = 0; k < 128; k += 4) {
      int prev = -1;
      float w0 = 0.f, w1_ = 0.f, w2_ = 0.f, w3 = 0.f;
      #pragma unroll
      for (int j = 0; j < 8; j++) {
        if (isos[j] != prev) {
          const float* wp = Wiso1 + isos[j] * 8192 + k * 64 + n;
          w0 = wp[0]; w1_ = wp[64]; w2_ = wp[128]; w3 = wp[192];
          prev = isos[j];
        }
        float4 h4 = *(const float4*)&shbuf[rows_[j] * 132 + k];
        acce[j] += h4.x * w0 + h4.y * w1_ + h4.z * w2_ + h4.w * w3;
      }
    }
    #pragma unroll
    for (int j = 0; j < 8; j++) {
      float p = wave_sum64(gelu_f(acce[j]) * Wiso2[isos[j] * 64 + n]);
      if (n == 0) eo[rows_[j]] = p + biso2[isos[j]];
    }
  }
  __syncthreads();                                    // B6

  // ---------------- epilogue: gated combine -------------------------------
  if (t < ROWS) {
    int r = t;
    float gate = gLUT[iso_s[r]];
    out[r0 + r] = gate * eo[r] + (1.0f - gate) * sp[r];
  }
}

extern "C" void kernel_launch(void* const* d_in, const int* in_sizes, int n_in,
                              void* d_out, int out_size, void* d_ws, size_t ws_size,
                              hipStream_t stream) {
  const float* x         = (const float*)d_in[0];
  const int*   mol_idx   = (const int*)  d_in[1];
  const int*   iso_idx   = (const int*)  d_in[2];
  const float* mol_embed = (const float*)d_in[3];
  const float* iso_embed = (const float*)d_in[4];
  const float* W1  = (const float*)d_in[5];
  const float* b1  = (const float*)d_in[6];
  const float* g1  = (const float*)d_in[7];
  const float* be1 = (const float*)d_in[8];
  const float* W2  = (const float*)d_in[9];
  const float* b2  = (const float*)d_in[10];
  const float* g2  = (const float*)d_in[11];
  const float* be2 = (const float*)d_in[12];
  const float* Wsh1 = (const float*)d_in[13];
  const float* bsh1 = (const float*)d_in[14];
  const float* Wsh2 = (const float*)d_in[15];
  const float* bsh2 = (const float*)d_in[16];
  const float* Wiso1 = (const float*)d_in[17];
  const float* biso1 = (const float*)d_in[18];
  const float* Wiso2 = (const float*)d_in[19];
  const float* biso2 = (const float*)d_in[20];
  const float* Wg = (const float*)d_in[21];
  const float* bg = (const float*)d_in[22];
  float* out = (float*)d_out;
  unsigned short* wsf = (unsigned short*)d_ws;   // needs 163840 B

  const int B = in_sizes[0] / 16;       // 262144
  const int grid = B / ROWS;            // 8192 blocks

  hipLaunchKernelGGL(prep_frags, dim3(40), dim3(256), 0, stream, W1, W2, wsf);
  hipLaunchKernelGGL(corr_reg_fused, dim3(grid), dim3(THREADS), 0, stream,
                     x, mol_idx, iso_idx, mol_embed, iso_embed,
                     b1, g1, be1, b2, g2, be2,
                     Wsh1, bsh1, Wsh2, bsh2,
                     Wiso1, biso1, Wiso2, biso2, Wg, bg, wsf, out);
}

// Round 4
// 251.436 us; speedup vs baseline: 19.9001x; 1.9742x over previous
//
#include <hip/hip_runtime.h>
#include <math.h>

// CorrectionRegressor fused kernel, round 4: everything matmul-shaped on MFMA.
// Layers 1+2: split-bf16 (3 MFMA). Heads: A-split x B-hi (2 MFMA), expert head
// block-diagonal via in-block iso-sorted 16-row tiles. Fast branch-free erf.
// B=262144 rows; per block: 32 rows, 256 threads (4 waves), 4 blocks/CU.

#define THREADS 256
#define ROWS 32

typedef __attribute__((ext_vector_type(8))) short short8;
typedef __attribute__((ext_vector_type(4))) float f32x4;

// d_ws layout in short8 (16 B) units:
#define W2F_OFF   0        // [h2][ks8][nt8][lane64]  = 8192 frags
#define W1F_OFF   8192     // [h2][nt16][lane64]      = 2048 frags
#define WSHF_OFF  10240    // [ks4][nt4][lane64]      = 1024 frags (hi only)
#define WISOF_OFF 11264    // [iso12][ks4][nt4][lane64]= 12288 frags (hi only)
#define F32_OFF   23552    // float region starts here (byte 376832):
                           //   contrib[12][64], gate[12]

__device__ __forceinline__ float gelu_f(float v) {
  // gelu(v) = 0.5 v (1 + erf(v/sqrt(2))), erf via A&S 7.1.26 (|eps|<=1.5e-7),
  // branch-free: abs+rcp+exp+4 fma poly.
  float x  = v * 0.70710678118654752f;
  float ax = __builtin_fabsf(x);
  float t  = __builtin_amdgcn_rcpf(__builtin_fmaf(0.3275911f, ax, 1.0f));
  float e  = __expf(-x * x);
  float p  = __builtin_fmaf(t, 1.061405429f, -1.453152027f);
  p = __builtin_fmaf(t, p, 1.421413741f);
  p = __builtin_fmaf(t, p, -0.284496736f);
  p = __builtin_fmaf(t, p, 0.254829592f);
  p = p * t;
  float r    = __builtin_fmaf(-p, e, 1.0f);
  float erfv = __builtin_copysignf(r, x);
  return 0.5f * v * (1.0f + erfv);
}
__device__ __forceinline__ unsigned short f2bf(float f) {   // RNE f32->bf16
  unsigned int u = __float_as_uint(f);
  return (unsigned short)((u + 0x7FFFu + ((u >> 16) & 1u)) >> 16);
}
__device__ __forceinline__ float bf2f(unsigned short b) {
  return __uint_as_float(((unsigned int)b) << 16);
}

// ---- prep: weight fragments + per-iso tables into d_ws -------------------
// frag value convention (both A and B sides share the k-map, so it cancels):
//   frag(lane l, j) = W[k = ks*32 + (l>>4)*8 + j][n = nt*16 + (l&15)]
__global__ void prep_frags(const float* __restrict__ W1, const float* __restrict__ W2,
                           const float* __restrict__ Wsh1, const float* __restrict__ bsh1,
                           const float* __restrict__ Wiso1,
                           const float* __restrict__ iso_embed,
                           const float* __restrict__ Wg, const float* __restrict__ bg,
                           unsigned short* __restrict__ wsf) {
  int id = blockIdx.x * 256 + threadIdx.x;
  float* wsc = (float*)(wsf + (size_t)F32_OFF * 8);
  if (id < 8192) {                      // W2 frags hi/lo
    int l = id & 63, nt = (id >> 6) & 7, ks = (id >> 9) & 7, h = id >> 12;
    int n = nt * 16 + (l & 15);
    int k0 = ks * 32 + (l >> 4) * 8;
    short8 pk;
    #pragma unroll
    for (int j = 0; j < 8; j++) {
      float v = W2[(k0 + j) * 128 + n];
      unsigned short hb = f2bf(v);
      pk[j] = (short)(h ? f2bf(v - bf2f(hb)) : hb);
    }
    *(short8*)(wsf + (size_t)id * 8) = pk;
  } else if (id < 10240) {              // W1 frags hi/lo
    int id2 = id - 8192;
    int l = id2 & 63, nt = (id2 >> 6) & 15, h = id2 >> 10;
    int n = nt * 16 + (l & 15);
    int k0 = (l >> 4) * 8;
    short8 pk;
    #pragma unroll
    for (int j = 0; j < 8; j++) {
      float v = W1[(k0 + j) * 256 + n];
      unsigned short hb = f2bf(v);
      pk[j] = (short)(h ? f2bf(v - bf2f(hb)) : hb);
    }
    *(short8*)(wsf + (size_t)id * 8) = pk;
  } else if (id < 11264) {              // Wsh1[:128] frags, hi only
    int fid = id - 10240;
    int l = fid & 63, nt = (fid >> 6) & 3, ks = fid >> 8;
    int n = nt * 16 + (l & 15);
    int k0 = ks * 32 + (l >> 4) * 8;
    short8 pk;
    #pragma unroll
    for (int j = 0; j < 8; j++) pk[j] = (short)f2bf(Wsh1[(k0 + j) * 64 + n]);
    *(short8*)(wsf + (size_t)id * 8) = pk;
  } else if (id < 23552) {              // Wiso1 frags, hi only
    int fid = id - 11264;
    int l = fid & 63, nt = (fid >> 6) & 3, ks = (fid >> 8) & 3, iso = fid >> 10;
    int n = nt * 16 + (l & 15);
    int k0 = ks * 32 + (l >> 4) * 8;
    short8 pk;
    #pragma unroll
    for (int j = 0; j < 8; j++) pk[j] = (short)f2bf(Wiso1[iso * 8192 + (k0 + j) * 64 + n]);
    *(short8*)(wsf + (size_t)id * 8) = pk;
  } else if (id < 24320) {              // contrib[i][n] = bsh1[n] + ie_i @ Wsh1[128:]
    int cid = id - 23552;
    int i = cid >> 6, n = cid & 63;
    float s = bsh1[n];
    #pragma unroll
    for (int e = 0; e < 8; e++) s += iso_embed[i * 8 + e] * Wsh1[(128 + e) * 64 + n];
    wsc[cid] = s;
  } else if (id < 24332) {              // gate[i] = sigmoid(ie_i @ Wg + bg)
    int i = id - 24320;
    float s = bg[0];
    #pragma unroll
    for (int e = 0; e < 8; e++) s += iso_embed[i * 8 + e] * Wg[e];
    wsc[768 + i] = 1.0f / (1.0f + expf(-s));
  }
}

__global__ __launch_bounds__(THREADS, 4)
void corr_reg_fused(
    const float* __restrict__ x,
    const int*   __restrict__ mol_idx,
    const int*   __restrict__ iso_idx,
    const float* __restrict__ mol_embed,
    const float* __restrict__ iso_embed,
    const float* __restrict__ b1,
    const float* __restrict__ g1,  const float* __restrict__ be1,
    const float* __restrict__ b2,
    const float* __restrict__ g2,  const float* __restrict__ be2,
    const float* __restrict__ bsh2,
    const float* __restrict__ Wsh2,
    const float* __restrict__ biso1,
    const float* __restrict__ Wiso2, const float* __restrict__ biso2,
    const unsigned short* __restrict__ wsf,
    float* __restrict__ out)
{
  // LDS = 40568 B -> 4 blocks/CU (4 x 40960 = 160 KiB exactly after 512B round)
  __shared__ float z[ROWS][36];                                // 4608
  __shared__ __align__(16) unsigned short hpool[2][ROWS][264]; // 33792 (h1 hi/lo; later aliased by sh planes)
  __shared__ float ps[4][ROWS], pq[4][ROWS];                   // 1024
  __shared__ float sp[ROWS], eo[ROWS];                         // 256
  __shared__ int   iso_s[ROWS];                                // 128
  __shared__ unsigned char rowlist[12][ROWS];                  // 384
  __shared__ unsigned char slots[256];                         // 256
  __shared__ short          tile_iso[16];                      // 32
  __shared__ unsigned short tile_sb[16];                       // 32
  __shared__ int rcount[12];                                   // 48
  __shared__ int ntiles, nslots;                               // 8

  unsigned short* sh_hi = &hpool[0][0][0];   // [32][136] bf16, alias (valid after B4)
  unsigned short* sh_lo = &hpool[1][0][0];

  const int t  = threadIdx.x;
  const int r0 = blockIdx.x * ROWS;
  const int l  = t & 63, w = t >> 6;
  const int lr = l & 15, lg = l >> 4;

  const short8* wsf8 = (const short8*)wsf;
  const float*  wsc  = (const float*)(wsf + (size_t)F32_OFF * 8);
  const float*  contrib = wsc;          // [12][64]
  const float*  gtab    = wsc + 768;    // [12]

  if (t < 12) rcount[t] = 0;
  if (t == 0) { ntiles = 2; nslots = 32; }
  if (t < 32) slots[t] = (unsigned char)t;      // shared-head tiles: identity rows
  if (t < 2)  { tile_iso[t] = -1; tile_sb[t] = (unsigned short)(16 * t); }
  __syncthreads();                                    // B0

  // ---------------- phase 0: stage z, iso lists ---------------------------
  if (t < 128) {
    float4 v = ((const float4*)(x + (size_t)r0 * 16))[t];
    int r = t >> 2, c = (t & 3) << 2;
    z[r][c] = v.x; z[r][c + 1] = v.y; z[r][c + 2] = v.z; z[r][c + 3] = v.w;
  }
  {
    int r = t >> 3, e = t & 7;
    int mi = mol_idx[r0 + r];
    int ii = iso_idx[r0 + r];
    z[r][16 + e] = mol_embed[mi * 8 + e];
    z[r][24 + e] = iso_embed[ii * 8 + e];
    if (e == 0) {
      iso_s[r] = ii;
      int pos = atomicAdd(&rcount[ii], 1);
      rowlist[ii][pos] = (unsigned char)r;
    }
  }
  __syncthreads();                                    // B1

  // build head tile list (12 threads, overlapped with layer-1 start)
  if (t < 12) {
    int c = rcount[t];
    int nsub = (c + 15) >> 4;
    if (nsub > 0) {
      int tb = atomicAdd(&ntiles, nsub);
      int sb = atomicAdd(&nslots, nsub << 4);
      for (int s2 = 0; s2 < nsub; s2++) {
        tile_iso[tb + s2] = (short)t;
        tile_sb[tb + s2]  = (unsigned short)(sb + (s2 << 4));
      }
      int tot = nsub << 4;
      for (int p = 0; p < tot; p++)
        slots[sb + p] = (p < c) ? rowlist[t][p] : (unsigned char)0xFF;
    }
  }

  // ---------------- layer 1 (MFMA): y1 = z @ W1 + b1 ----------------------
  f32x4 acc[2][4];
  {
    short8 zah[2], zal[2];
    #pragma unroll
    for (int mt = 0; mt < 2; mt++) {
      int row = mt * 16 + lr;
      float vv[8];
      *(float4*)&vv[0] = *(const float4*)&z[row][lg * 8];
      *(float4*)&vv[4] = *(const float4*)&z[row][lg * 8 + 4];
      short8 h8, l8;
      #pragma unroll
      for (int j = 0; j < 8; j++) {
        unsigned short hb = f2bf(vv[j]);
        unsigned short lb = f2bf(vv[j] - bf2f(hb));
        h8[j] = (short)hb; l8[j] = (short)lb;
      }
      zah[mt] = h8; zal[mt] = l8;
    }
    const short8* w1p = wsf8 + W1F_OFF;
    short8 bh[4], bl[4];
    #pragma unroll
    for (int q = 0; q < 4; q++) {
      int nt = w * 4 + q;
      bh[q] = w1p[nt * 64 + l];
      bl[q] = w1p[(16 + nt) * 64 + l];
    }
    #pragma unroll
    for (int mt = 0; mt < 2; mt++)
      #pragma unroll
      for (int q = 0; q < 4; q++) {
        f32x4 a_ = {0.f, 0.f, 0.f, 0.f};
        a_ = __builtin_amdgcn_mfma_f32_16x16x32_bf16(zah[mt], bh[q], a_, 0, 0, 0);
        a_ = __builtin_amdgcn_mfma_f32_16x16x32_bf16(zah[mt], bl[q], a_, 0, 0, 0);
        a_ = __builtin_amdgcn_mfma_f32_16x16x32_bf16(zal[mt], bh[q], a_, 0, 0, 0);
        acc[mt][q] = a_;
      }
    float bc[4];
    #pragma unroll
    for (int q = 0; q < 4; q++) bc[q] = b1[(w * 4 + q) * 16 + lr];
    #pragma unroll
    for (int mt = 0; mt < 2; mt++)
      #pragma unroll
      for (int q = 0; q < 4; q++)
        #pragma unroll
        for (int i = 0; i < 4; i++) acc[mt][q][i] += bc[q];
    #pragma unroll
    for (int mt = 0; mt < 2; mt++)
      #pragma unroll
      for (int i = 0; i < 4; i++) {
        float sm = acc[mt][0][i] + acc[mt][1][i] + acc[mt][2][i] + acc[mt][3][i];
        float sq = acc[mt][0][i]*acc[mt][0][i] + acc[mt][1][i]*acc[mt][1][i]
                 + acc[mt][2][i]*acc[mt][2][i] + acc[mt][3][i]*acc[mt][3][i];
        #pragma unroll
        for (int m = 1; m < 16; m <<= 1) { sm += __shfl_xor(sm, m); sq += __shfl_xor(sq, m); }
        if (lr == 0) { ps[w][mt * 16 + lg * 4 + i] = sm; pq[w][mt * 16 + lg * 4 + i] = sq; }
      }
  }
  __syncthreads();                                    // B2

  // ---------------- LN1 + GELU + bf16 split -> h fragments ----------------
  {
    float g1c[4], be1c[4];
    #pragma unroll
    for (int q = 0; q < 4; q++) {
      int col = (w * 4 + q) * 16 + lr;
      g1c[q] = g1[col]; be1c[q] = be1[col];
    }
    #pragma unroll
    for (int mt = 0; mt < 2; mt++)
      #pragma unroll
      for (int i = 0; i < 4; i++) {
        int row = mt * 16 + lg * 4 + i;
        float su = ps[0][row] + ps[1][row] + ps[2][row] + ps[3][row];
        float s2 = pq[0][row] + pq[1][row] + pq[2][row] + pq[3][row];
        float mu = su * (1.0f / 256.0f);
        float var = s2 * (1.0f / 256.0f) - mu * mu;
        float rs = rsqrtf(var + 1e-5f);
        #pragma unroll
        for (int q = 0; q < 4; q++) {
          int col = (w * 4 + q) * 16 + lr;
          float h = gelu_f((acc[mt][q][i] - mu) * rs * g1c[q] + be1c[q]);
          unsigned short hb = f2bf(h);
          unsigned short lb = f2bf(h - bf2f(hb));
          hpool[0][row][col] = hb;
          hpool[1][row][col] = lb;
        }
      }
  }
  __syncthreads();                                    // B3

  // ---------------- layer 2 (MFMA): y2 = h1 @ W2 + b2 ---------------------
  f32x4 a2[2][2];
  {
    #pragma unroll
    for (int mt = 0; mt < 2; mt++)
      #pragma unroll
      for (int q = 0; q < 2; q++) { f32x4 zf = {0.f,0.f,0.f,0.f}; a2[mt][q] = zf; }
    const short8* w2p = wsf8 + W2F_OFF;
    for (int ks = 0; ks < 8; ks++) {
      int k0 = ks * 32 + lg * 8;
      short8 ah0 = *(const short8*)&hpool[0][lr][k0];
      short8 al0 = *(const short8*)&hpool[1][lr][k0];
      short8 ah1 = *(const short8*)&hpool[0][16 + lr][k0];
      short8 al1 = *(const short8*)&hpool[1][16 + lr][k0];
      short8 bh0 = w2p[(ks * 8 + 2 * w + 0) * 64 + l];
      short8 bl0 = w2p[((8 + ks) * 8 + 2 * w + 0) * 64 + l];
      short8 bh1 = w2p[(ks * 8 + 2 * w + 1) * 64 + l];
      short8 bl1 = w2p[((8 + ks) * 8 + 2 * w + 1) * 64 + l];
      a2[0][0] = __builtin_amdgcn_mfma_f32_16x16x32_bf16(ah0, bh0, a2[0][0], 0, 0, 0);
      a2[0][0] = __builtin_amdgcn_mfma_f32_16x16x32_bf16(ah0, bl0, a2[0][0], 0, 0, 0);
      a2[0][0] = __builtin_amdgcn_mfma_f32_16x16x32_bf16(al0, bh0, a2[0][0], 0, 0, 0);
      a2[0][1] = __builtin_amdgcn_mfma_f32_16x16x32_bf16(ah0, bh1, a2[0][1], 0, 0, 0);
      a2[0][1] = __builtin_amdgcn_mfma_f32_16x16x32_bf16(ah0, bl1, a2[0][1], 0, 0, 0);
      a2[0][1] = __builtin_amdgcn_mfma_f32_16x16x32_bf16(al0, bh1, a2[0][1], 0, 0, 0);
      a2[1][0] = __builtin_amdgcn_mfma_f32_16x16x32_bf16(ah1, bh0, a2[1][0], 0, 0, 0);
      a2[1][0] = __builtin_amdgcn_mfma_f32_16x16x32_bf16(ah1, bl0, a2[1][0], 0, 0, 0);
      a2[1][0] = __builtin_amdgcn_mfma_f32_16x16x32_bf16(al1, bh0, a2[1][0], 0, 0, 0);
      a2[1][1] = __builtin_amdgcn_mfma_f32_16x16x32_bf16(ah1, bh1, a2[1][1], 0, 0, 0);
      a2[1][1] = __builtin_amdgcn_mfma_f32_16x16x32_bf16(ah1, bl1, a2[1][1], 0, 0, 0);
      a2[1][1] = __builtin_amdgcn_mfma_f32_16x16x32_bf16(al1, bh1, a2[1][1], 0, 0, 0);
    }
    float bc2[2];
    #pragma unroll
    for (int q = 0; q < 2; q++) bc2[q] = b2[(2 * w + q) * 16 + lr];
    #pragma unroll
    for (int mt = 0; mt < 2; mt++)
      #pragma unroll
      for (int q = 0; q < 2; q++)
        #pragma unroll
        for (int i = 0; i < 4; i++) a2[mt][q][i] += bc2[q];
    #pragma unroll
    for (int mt = 0; mt < 2; mt++)
      #pragma unroll
      for (int i = 0; i < 4; i++) {
        float sm = a2[mt][0][i] + a2[mt][1][i];
        float sq = a2[mt][0][i]*a2[mt][0][i] + a2[mt][1][i]*a2[mt][1][i];
        #pragma unroll
        for (int m = 1; m < 16; m <<= 1) { sm += __shfl_xor(sm, m); sq += __shfl_xor(sq, m); }
        if (lr == 0) { ps[w][mt * 16 + lg * 4 + i] = sm; pq[w][mt * 16 + lg * 4 + i] = sq; }
      }
  }
  __syncthreads();                                    // B4 (all hpool reads done)

  // ---------------- LN2 + GELU -> shared bf16 hi/lo planes (alias) --------
  {
    float g2c[2], be2c[2];
    #pragma unroll
    for (int q = 0; q < 2; q++) {
      int col = (2 * w + q) * 16 + lr;
      g2c[q] = g2[col]; be2c[q] = be2[col];
    }
    #pragma unroll
    for (int mt = 0; mt < 2; mt++)
      #pragma unroll
      for (int i = 0; i < 4; i++) {
        int row = mt * 16 + lg * 4 + i;
        float su = ps[0][row] + ps[1][row] + ps[2][row] + ps[3][row];
        float s2 = pq[0][row] + pq[1][row] + pq[2][row] + pq[3][row];
        float mu = su * (1.0f / 128.0f);
        float var = s2 * (1.0f / 128.0f) - mu * mu;
        float rs = rsqrtf(var + 1e-5f);
        #pragma unroll
        for (int q = 0; q < 2; q++) {
          int col = (2 * w + q) * 16 + lr;
          float h = gelu_f((a2[mt][q][i] - mu) * rs * g2c[q] + be2c[q]);
          unsigned short hb = f2bf(h);
          unsigned short lb = f2bf(h - bf2f(hb));
          sh_hi[row * 136 + col] = hb;
          sh_lo[row * 136 + col] = lb;
        }
      }
  }
  __syncthreads();                                    // B5

  // ---------------- heads: unified MFMA tile loop --------------------------
  {
    float wsh2c[4];
    #pragma unroll
    for (int nt = 0; nt < 4; nt++) wsh2c[nt] = Wsh2[nt * 16 + lr];
    float bsh2v = bsh2[0];
    int ntl = ntiles;
    for (int tt = w; tt < ntl; tt += 4) {
      int iso = tile_iso[tt];             // -1 => shared head tile
      int sb  = tile_sb[tt];
      int ar  = slots[sb + lr] & 31;      // pad (0xFF) -> row 31 reads, write-masked
      short8 a_hi[4], a_lo[4];
      #pragma unroll
      for (int ks = 0; ks < 4; ks++) {
        int off = ar * 136 + ks * 32 + lg * 8;
        a_hi[ks] = *(const short8*)&sh_hi[off];
        a_lo[ks] = *(const short8*)&sh_lo[off];
      }
      const short8* bp = (iso < 0) ? (wsf8 + WSHF_OFF) : (wsf8 + WISOF_OFF + iso * 1024);
      f32x4 c[4];
      #pragma unroll
      for (int nt = 0; nt < 4; nt++) { f32x4 zf = {0.f,0.f,0.f,0.f}; c[nt] = zf; }
      #pragma unroll
      for (int ks = 0; ks < 4; ks++)
        #pragma unroll
        for (int nt = 0; nt < 4; nt++) {
          short8 b = bp[(ks * 4 + nt) * 64 + l];
          c[nt] = __builtin_amdgcn_mfma_f32_16x16x32_bf16(a_hi[ks], b, c[nt], 0, 0, 0);
          c[nt] = __builtin_amdgcn_mfma_f32_16x16x32_bf16(a_lo[ks], b, c[nt], 0, 0, 0);
        }
      int rws[4];
      #pragma unroll
      for (int i = 0; i < 4; i++) rws[i] = slots[sb + lg * 4 + i];
      float accv[4];
      if (iso < 0) {
        #pragma unroll
        for (int i = 0; i < 4; i++) {
          const float* cb = contrib + iso_s[rws[i]] * 64;
          float a = 0.f;
          #pragma unroll
          for (int nt = 0; nt < 4; nt++)
            a += gelu_f(c[nt][i] + cb[nt * 16 + lr]) * wsh2c[nt];
          accv[i] = a;
        }
      } else {
        float bcol[4], wcol[4];
        #pragma unroll
        for (int nt = 0; nt < 4; nt++) {
          int col = iso * 64 + nt * 16 + lr;
          bcol[nt] = biso1[col];
          wcol[nt] = Wiso2[col];
        }
        #pragma unroll
        for (int i = 0; i < 4; i++) {
          float a = 0.f;
          #pragma unroll
          for (int nt = 0; nt < 4; nt++)
            a += gelu_f(c[nt][i] + bcol[nt]) * wcol[nt];
          accv[i] = a;
        }
      }
      float tail = (iso < 0) ? bsh2v : biso2[iso];
      #pragma unroll
      for (int i = 0; i < 4; i++) {
        float a = accv[i];
        a += __shfl_xor(a, 1); a += __shfl_xor(a, 2);
        a += __shfl_xor(a, 4); a += __shfl_xor(a, 8);
        if (lr == 0) {
          int r = rws[i];
          if (iso < 0) sp[r] = a + tail;
          else if (r != 0xFF) eo[r] = a + tail;
        }
      }
    }
  }
  __syncthreads();                                    // B6

  // ---------------- epilogue: gated combine -------------------------------
  if (t < ROWS) {
    int r = t;
    float gate = gtab[iso_s[r]];
    out[r0 + r] = gate * eo[r] + (1.0f - gate) * sp[r];
  }
}

extern "C" void kernel_launch(void* const* d_in, const int* in_sizes, int n_in,
                              void* d_out, int out_size, void* d_ws, size_t ws_size,
                              hipStream_t stream) {
  const float* x         = (const float*)d_in[0];
  const int*   mol_idx   = (const int*)  d_in[1];
  const int*   iso_idx   = (const int*)  d_in[2];
  const float* mol_embed = (const float*)d_in[3];
  const float* iso_embed = (const float*)d_in[4];
  const float* W1  = (const float*)d_in[5];
  const float* b1  = (const float*)d_in[6];
  const float* g1  = (const float*)d_in[7];
  const float* be1 = (const float*)d_in[8];
  const float* W2  = (const float*)d_in[9];
  const float* b2  = (const float*)d_in[10];
  const float* g2  = (const float*)d_in[11];
  const float* be2 = (const float*)d_in[12];
  const float* Wsh1 = (const float*)d_in[13];
  const float* bsh1 = (const float*)d_in[14];
  const float* Wsh2 = (const float*)d_in[15];
  const float* bsh2 = (const float*)d_in[16];
  const float* Wiso1 = (const float*)d_in[17];
  const float* biso1 = (const float*)d_in[18];
  const float* Wiso2 = (const float*)d_in[19];
  const float* biso2 = (const float*)d_in[20];
  const float* Wg = (const float*)d_in[21];
  const float* bg = (const float*)d_in[22];
  float* out = (float*)d_out;
  unsigned short* wsf = (unsigned short*)d_ws;   // needs ~380 KB

  const int B = in_sizes[0] / 16;       // 262144
  const int grid = B / ROWS;            // 8192 blocks

  hipLaunchKernelGGL(prep_frags, dim3(96), dim3(256), 0, stream,
                     W1, W2, Wsh1, bsh1, Wiso1, iso_embed, Wg, bg, wsf);
  hipLaunchKernelGGL(corr_reg_fused, dim3(grid), dim3(THREADS), 0, stream,
                     x, mol_idx, iso_idx, mol_embed, iso_embed,
                     b1, g1, be1, b2, g2, be2,
                     bsh2, Wsh2, biso1, Wiso2, biso2, wsf, out);
}